// Round 1
// baseline (354.458 us; speedup 1.0000x reference)
//
#include <hip/hip_runtime.h>
#include <hip/hip_bf16.h>

#define B_   256
#define L_   64
#define E_   128
#define S_   16
#define H0_  2048
#define H1_  512
#define LE_  8192
#define DIN_ 8336

typedef __attribute__((ext_vector_type(8))) short short8_t;
typedef __attribute__((ext_vector_type(4))) float f32x4;

static __device__ __forceinline__ f32x4 mfma16(short8_t a, short8_t b, f32x4 c){
  return __builtin_amdgcn_mfma_f32_16x16x32_bf16(a, b, c, 0, 0, 0);
}

static __device__ __forceinline__ unsigned short f2bf(float x){
  unsigned u = __builtin_bit_cast(unsigned, x);
  unsigned r = u + 0x7FFFu + ((u >> 16) & 1u);
  return (unsigned short)(r >> 16);
}

// ---------- transpose + fp32->bf16 : src[R][C] -> dst[C][R] ----------
__global__ __launch_bounds__(256) void k_transpose_cvt(const float* __restrict__ src,
    unsigned short* __restrict__ dst, int R, int C){
  __shared__ unsigned short tile[64][65];
  int R0 = blockIdx.x * 64, C0 = blockIdx.y * 64;
  int t = threadIdx.x;
  int row = t >> 2, c16 = (t & 3) * 16;
  int gr = R0 + row;
  if (gr < R){
    const float* p = src + (size_t)gr * C + C0 + c16;
    #pragma unroll
    for (int j = 0; j < 16; j += 4){
      float4 v = *reinterpret_cast<const float4*>(p + j);
      tile[row][c16+j+0] = f2bf(v.x);
      tile[row][c16+j+1] = f2bf(v.y);
      tile[row][c16+j+2] = f2bf(v.z);
      tile[row][c16+j+3] = f2bf(v.w);
    }
  }
  __syncthreads();
  int orow = t >> 2, r16 = (t & 3) * 16;
  unsigned short* q = dst + (size_t)(C0 + orow) * R + R0 + r16;
  #pragma unroll
  for (int j = 0; j < 16; ++j){
    if (R0 + r16 + j < R) q[j] = tile[r16 + j][orow];
  }
}

// ---------- gather + row-normalize -> bf16, one wave per (b,l) row ----------
__global__ __launch_bounds__(256) void k_gather(const int* __restrict__ tokens,
    const float* __restrict__ emb, unsigned short* __restrict__ ebf){
  int wid  = blockIdx.x * 4 + (threadIdx.x >> 6);   // row 0..16383
  int lane = threadIdx.x & 63;
  int tok  = tokens[wid];
  const float* row = emb + (size_t)tok * E_;
  float2 v = *reinterpret_cast<const float2*>(row + lane * 2);
  float ss = v.x * v.x + v.y * v.y;
  #pragma unroll
  for (int m = 1; m < 64; m <<= 1) ss += __shfl_xor(ss, m, 64);
  float nrm = sqrtf(ss);
  float scale = (nrm > 1.0f) ? 1.0f / (nrm + 1e-7f) : 1.0f;
  unsigned a = f2bf(v.x * scale), b = f2bf(v.y * scale);
  *reinterpret_cast<unsigned*>(ebf + (size_t)wid * E_ + lane * 2) = a | (b << 16);
}

// ---------- base = b0 + sv @ W_snt ----------
__global__ __launch_bounds__(256) void k_base_init(const int* __restrict__ sid,
    const float* __restrict__ stab, const float* __restrict__ W0,
    const float* __restrict__ b0, float* __restrict__ base){
  int idx = blockIdx.x * 256 + threadIdx.x;   // over B*H0
  int b = idx >> 11, h = idx & 2047;
  const float* sv = stab + sid[b] * S_;
  float acc = b0[h];
  #pragma unroll
  for (int s = 0; s < S_; ++s) acc += sv[s] * W0[(size_t)(LE_ + s) * H0_ + h];
  base[idx] = acc;
}

// ---------- base += sent_flat @ W_sent  (K-split, fp32 atomics) ----------
__global__ __launch_bounds__(256) void k_gemmA(const unsigned short* __restrict__ ebf,
    const unsigned short* __restrict__ W0T, float* __restrict__ base){
  int bid = blockIdx.x;
  int mt = bid & 3, nt = (bid >> 2) & 15, kw = bid >> 6;
  int m0 = mt * 64, n0 = nt * 128, k0 = kw * 2048;
  __shared__ unsigned short Al[64][72];
  __shared__ unsigned short Bl[128][72];
  int t = threadIdx.x, lane = t & 63, w = t >> 6;
  int wm = w >> 1, wn = w & 1;           // wave tile 32 x 64
  f32x4 acc[2][4];
  #pragma unroll
  for (int m = 0; m < 2; ++m)
    #pragma unroll
    for (int n = 0; n < 4; ++n) acc[m][n] = (f32x4){0.f,0.f,0.f,0.f};

  for (int it = 0; it < 32; ++it){
    int kb = k0 + it * 64;
    __syncthreads();
    { // stage A 64x64
      int row = t >> 2, kc = (t & 3) * 16;
      const short8_t* g = reinterpret_cast<const short8_t*>(ebf + (size_t)(m0 + row) * LE_ + kb + kc);
      *reinterpret_cast<short8_t*>(&Al[row][kc])     = g[0];
      *reinterpret_cast<short8_t*>(&Al[row][kc + 8]) = g[1];
    }
    { // stage B 128x64 from W0T
      int row = t >> 1, kc = (t & 1) * 32;
      const unsigned short* g = W0T + (size_t)(n0 + row) * DIN_ + kb + kc;
      #pragma unroll
      for (int j = 0; j < 32; j += 8)
        *reinterpret_cast<short8_t*>(&Bl[row][kc + j]) = *reinterpret_cast<const short8_t*>(g + j);
    }
    __syncthreads();
    #pragma unroll
    for (int ks = 0; ks < 2; ++ks){
      short8_t af[2], bfr[4];
      #pragma unroll
      for (int m = 0; m < 2; ++m)
        af[m] = *reinterpret_cast<const short8_t*>(&Al[wm*32 + m*16 + (lane & 15)][ks*32 + (lane >> 4) * 8]);
      #pragma unroll
      for (int n = 0; n < 4; ++n)
        bfr[n] = *reinterpret_cast<const short8_t*>(&Bl[wn*64 + n*16 + (lane & 15)][ks*32 + (lane >> 4) * 8]);
      #pragma unroll
      for (int m = 0; m < 2; ++m)
        #pragma unroll
        for (int n = 0; n < 4; ++n) acc[m][n] = mfma16(af[m], bfr[n], acc[m][n]);
    }
  }
  int r0 = m0 + wm * 32, c0 = n0 + wn * 64;
  #pragma unroll
  for (int m = 0; m < 2; ++m)
    #pragma unroll
    for (int n = 0; n < 4; ++n)
      #pragma unroll
      for (int i = 0; i < 4; ++i){
        int r = r0 + m * 16 + (lane >> 4) * 4 + i;
        int c = c0 + n * 16 + (lane & 15);
        atomicAdd(&base[(size_t)r * H0_ + c], acc[m][n][i]);
      }
}

// ---------- fused: h0 = relu(base + ebf@W_word); h1 = relu(h0@W1 + b1); pred ----------
__global__ __launch_bounds__(512) void k_gemmC(const unsigned short* __restrict__ ebf,
    const unsigned short* __restrict__ W0T, const unsigned short* __restrict__ W1T,
    const float* __restrict__ base, const float* __restrict__ b1,
    const float* __restrict__ Wp, const float* __restrict__ bp,
    const int* __restrict__ lens, float* __restrict__ out){
  int blk = blockIdx.x;                       // sentence b; rows l=0..63
  int t = threadIdx.x, lane = t & 63, w = t >> 6;   // 8 waves
  int wm = w >> 2, wn = w & 3;               // main wave tile: 32 rows x 128 cols
  __shared__ unsigned short Ae[64][136];
  __shared__ unsigned short Bw[128][136];
  __shared__ unsigned short Hs[64][136];
  __shared__ unsigned short W1s[512][40];
  __shared__ float base_s[H0_];
  __shared__ float logit_s[64];

  { // stage ebf rows for this sentence (once)
    int row = t >> 3, kc = (t & 7) * 16;
    const short8_t* g = reinterpret_cast<const short8_t*>(ebf + (size_t)(blk * 64 + row) * E_ + kc);
    *reinterpret_cast<short8_t*>(&Ae[row][kc])     = g[0];
    *reinterpret_cast<short8_t*>(&Ae[row][kc + 8]) = g[1];
  }
  { // stage base vector (once)
    float4 v = *reinterpret_cast<const float4*>(base + (size_t)blk * H0_ + t * 4);
    *reinterpret_cast<float4*>(&base_s[t * 4]) = v;
  }
  if (t < 64) logit_s[t] = 0.f;

  f32x4 acc[2][8];
  #pragma unroll
  for (int m = 0; m < 2; ++m)
    #pragma unroll
    for (int n = 0; n < 8; ++n) acc[m][n] = (f32x4){0.f,0.f,0.f,0.f};

  for (int c = 0; c < 16; ++c){
    __syncthreads();
    { // stage W_word^T chunk: W0T rows c*128..+127, cols 8208..8335
      int row = t >> 2, kc = (t & 3) * 32;
      const unsigned short* g = W0T + (size_t)(c * 128 + row) * DIN_ + (LE_ + S_) + kc;
      #pragma unroll
      for (int j = 0; j < 32; j += 8)
        *reinterpret_cast<short8_t*>(&Bw[row][kc + j]) = *reinterpret_cast<const short8_t*>(g + j);
    }
    __syncthreads();
    // mini-GEMM: h0 chunk (64 x 128), wave tile 32x32
    f32x4 a2[2][2];
    #pragma unroll
    for (int m = 0; m < 2; ++m)
      #pragma unroll
      for (int n = 0; n < 2; ++n) a2[m][n] = (f32x4){0.f,0.f,0.f,0.f};
    #pragma unroll
    for (int ks = 0; ks < 4; ++ks){
      short8_t af[2], bfr[2];
      #pragma unroll
      for (int m = 0; m < 2; ++m)
        af[m] = *reinterpret_cast<const short8_t*>(&Ae[wm*32 + m*16 + (lane & 15)][ks*32 + (lane >> 4) * 8]);
      #pragma unroll
      for (int n = 0; n < 2; ++n)
        bfr[n] = *reinterpret_cast<const short8_t*>(&Bw[wn*32 + n*16 + (lane & 15)][ks*32 + (lane >> 4) * 8]);
      #pragma unroll
      for (int m = 0; m < 2; ++m)
        #pragma unroll
        for (int n = 0; n < 2; ++n) a2[m][n] = mfma16(af[m], bfr[n], a2[m][n]);
    }
    #pragma unroll
    for (int m = 0; m < 2; ++m)
      #pragma unroll
      for (int n = 0; n < 2; ++n)
        #pragma unroll
        for (int i = 0; i < 4; ++i){
          int row = wm*32 + m*16 + (lane >> 4) * 4 + i;
          int col = wn*32 + n*16 + (lane & 15);
          float v = a2[m][n][i] + base_s[c * 128 + col];
          Hs[row][col] = f2bf(v > 0.f ? v : 0.f);
        }
    __syncthreads();
    // main accumulate: h1 += h0chunk @ W1chunk, 4 sub-steps of K=32
    for (int kk = 0; kk < 4; ++kk){
      if (kk) __syncthreads();
      { // stage W1T sub: 512 cols x 32 k
        const unsigned short* g = W1T + (size_t)t * H0_ + c * 128 + kk * 32;
        #pragma unroll
        for (int j = 0; j < 32; j += 8)
          *reinterpret_cast<short8_t*>(&W1s[t][j]) = *reinterpret_cast<const short8_t*>(g + j);
      }
      __syncthreads();
      short8_t af[2], bfr[8];
      #pragma unroll
      for (int m = 0; m < 2; ++m)
        af[m] = *reinterpret_cast<const short8_t*>(&Hs[wm*32 + m*16 + (lane & 15)][kk*32 + (lane >> 4) * 8]);
      #pragma unroll
      for (int n = 0; n < 8; ++n)
        bfr[n] = *reinterpret_cast<const short8_t*>(&W1s[wn*128 + n*16 + (lane & 15)][(lane >> 4) * 8]);
      #pragma unroll
      for (int m = 0; m < 2; ++m)
        #pragma unroll
        for (int n = 0; n < 8; ++n) acc[m][n] = mfma16(af[m], bfr[n], acc[m][n]);
    }
  }
  // epilogue: h1 = relu(acc + b1); logit = h1 . Wp
  float b1v[8], wpv[8];
  #pragma unroll
  for (int n = 0; n < 8; ++n){
    int col = wn*128 + n*16 + (lane & 15);
    b1v[n] = b1[col]; wpv[n] = Wp[col];
  }
  #pragma unroll
  for (int m = 0; m < 2; ++m)
    #pragma unroll
    for (int i = 0; i < 4; ++i){
      float p = 0.f;
      #pragma unroll
      for (int n = 0; n < 8; ++n){
        float h = acc[m][n][i] + b1v[n];
        h = h > 0.f ? h : 0.f;
        p += h * wpv[n];
      }
      p += __shfl_xor(p, 1); p += __shfl_xor(p, 2);
      p += __shfl_xor(p, 4); p += __shfl_xor(p, 8);
      if ((lane & 15) == 0)
        atomicAdd(&logit_s[wm*32 + m*16 + (lane >> 4) * 4 + i], p);
    }
  __syncthreads();
  if (t < 64){
    int len = lens[blk];
    float bpv = bp[0];
    float x = (t < len) ? (logit_s[t] + bpv) : bpv;
    out[blk * 64 + t] = 1.f / (1.f + expf(-x));
  }
}

extern "C" void kernel_launch(void* const* d_in, const int* in_sizes, int n_in,
                              void* d_out, int out_size, void* d_ws, size_t ws_size,
                              hipStream_t stream){
  const int*   text = (const int*)d_in[0];
  const int*   lens = (const int*)d_in[1];
  const int*   sid  = (const int*)d_in[2];
  const float* emb  = (const float*)d_in[3];
  const float* stab = (const float*)d_in[4];
  const float* W0   = (const float*)d_in[5];
  const float* b0   = (const float*)d_in[6];
  const float* W1   = (const float*)d_in[7];
  const float* b1   = (const float*)d_in[8];
  const float* Wp   = (const float*)d_in[9];
  const float* bp   = (const float*)d_in[10];
  float* out = (float*)d_out;

  char* ws = (char*)d_ws;
  unsigned short* ebf = (unsigned short*)(ws);                 //  4,194,304 B
  unsigned short* W0T = (unsigned short*)(ws + 4194304);       // 34,144,256 B
  unsigned short* W1T = (unsigned short*)(ws + 38338560);      //  2,097,152 B
  float*          base = (float*)(ws + 40435712);              //  2,097,152 B

  hipLaunchKernelGGL(k_transpose_cvt, dim3(131, 32), dim3(256), 0, stream, W0, W0T, DIN_, H0_);
  hipLaunchKernelGGL(k_transpose_cvt, dim3(32, 8),   dim3(256), 0, stream, W1, W1T, H0_, H1_);
  hipLaunchKernelGGL(k_gather,    dim3(4096), dim3(256), 0, stream, text, emb, ebf);
  hipLaunchKernelGGL(k_base_init, dim3(2048), dim3(256), 0, stream, sid, stab, W0, b0, base);
  hipLaunchKernelGGL(k_gemmA,     dim3(256),  dim3(256), 0, stream, ebf, W0T, base);
  hipLaunchKernelGGL(k_gemmC,     dim3(256),  dim3(512), 0, stream, ebf, W0T, W1T, base, b1, Wp, bp, lens, out);
}

// Round 2
// 285.111 us; speedup vs baseline: 1.2432x; 1.2432x over previous
//
#include <hip/hip_runtime.h>
#include <hip/hip_bf16.h>

#define B_   256
#define L_   64
#define E_   128
#define S_   16
#define H0_  2048
#define H1_  512
#define LE_  8192
#define DIN_ 8336
#define NROW 16384

typedef __attribute__((ext_vector_type(8))) short short8_t;
typedef __attribute__((ext_vector_type(4))) float f32x4;

static __device__ __forceinline__ f32x4 mfma16(short8_t a, short8_t b, f32x4 c){
  return __builtin_amdgcn_mfma_f32_16x16x32_bf16(a, b, c, 0, 0, 0);
}

static __device__ __forceinline__ unsigned short f2bf(float x){
  unsigned u = __builtin_bit_cast(unsigned, x);
  unsigned r = u + 0x7FFFu + ((u >> 16) & 1u);
  return (unsigned short)(r >> 16);
}

// async global->LDS, 16B per lane; LDS dest = wave-uniform base + lane*16
static __device__ __forceinline__ void gl_lds16(const void* g, void* l){
  __builtin_amdgcn_global_load_lds((const __attribute__((address_space(1))) unsigned*)g,
                                   (__attribute__((address_space(3))) unsigned*)l, 16, 0, 0);
}

// ---------- prefix scan over lengths -> rowmap/offs/meta ----------
__global__ __launch_bounds__(256) void k_scan(const int* __restrict__ lens,
    int* __restrict__ rowmap, int* __restrict__ offs, int* __restrict__ meta){
  __shared__ int sh[256];
  int t = threadIdx.x;
  int v = lens[t];
  sh[t] = v;
  __syncthreads();
  for (int d = 1; d < 256; d <<= 1){
    int y = (t >= d) ? sh[t - d] : 0;
    __syncthreads();
    sh[t] += y;
    __syncthreads();
  }
  int off = sh[t] - v;
  int nv = sh[255];
  offs[t] = off;
  if (t == 0){ meta[0] = nv; meta[1] = (nv + 127) & ~127; }
  for (int l = 0; l < v; ++l) rowmap[off + l] = t * 64 + l;
  for (int i = nv + t; i < NROW; i += 256) rowmap[i] = 0;
}

// ---------- transpose + fp32->bf16 : src[R][C] -> dst[C][R] ----------
__global__ __launch_bounds__(256) void k_transpose_cvt(const float* __restrict__ src,
    unsigned short* __restrict__ dst, int R, int C){
  __shared__ unsigned short tile[64][65];
  int R0 = blockIdx.x * 64, C0 = blockIdx.y * 64;
  int t = threadIdx.x;
  int row = t >> 2, c16 = (t & 3) * 16;
  int gr = R0 + row;
  if (gr < R){
    const float* p = src + (size_t)gr * C + C0 + c16;
    #pragma unroll
    for (int j = 0; j < 16; j += 4){
      float4 v = *reinterpret_cast<const float4*>(p + j);
      tile[row][c16+j+0] = f2bf(v.x);
      tile[row][c16+j+1] = f2bf(v.y);
      tile[row][c16+j+2] = f2bf(v.z);
      tile[row][c16+j+3] = f2bf(v.w);
    }
  }
  __syncthreads();
  int orow = t >> 2, r16 = (t & 3) * 16;
  unsigned short buf[16];
  #pragma unroll
  for (int j = 0; j < 16; ++j) buf[j] = tile[r16 + j][orow];
  unsigned short* q = dst + (size_t)(C0 + orow) * R + R0 + r16;
  if (R0 + r16 + 15 < R){
    *reinterpret_cast<short8_t*>(q)     = *reinterpret_cast<short8_t*>(&buf[0]);
    *reinterpret_cast<short8_t*>(q + 8) = *reinterpret_cast<short8_t*>(&buf[8]);
  } else {
    for (int j = 0; j < 16; ++j) if (R0 + r16 + j < R) q[j] = buf[j];
  }
}

// ---------- gather + row-normalize -> bf16, one wave per (b,l) row ----------
__global__ __launch_bounds__(256) void k_gather(const int* __restrict__ tokens,
    const float* __restrict__ emb, unsigned short* __restrict__ ebf){
  int wid  = blockIdx.x * 4 + (threadIdx.x >> 6);
  int lane = threadIdx.x & 63;
  int tok  = tokens[wid];
  const float* row = emb + (size_t)tok * E_;
  float2 v = *reinterpret_cast<const float2*>(row + lane * 2);
  float ss = v.x * v.x + v.y * v.y;
  #pragma unroll
  for (int m = 1; m < 64; m <<= 1) ss += __shfl_xor(ss, m, 64);
  float nrm = sqrtf(ss);
  float scale = (nrm > 1.0f) ? 1.0f / (nrm + 1e-7f) : 1.0f;
  unsigned a = f2bf(v.x * scale), b = f2bf(v.y * scale);
  *reinterpret_cast<unsigned*>(ebf + (size_t)wid * E_ + lane * 2) = a | (b << 16);
}

// ---------- part[kw] = sent_flat @ W_sent (K-split, no atomics) ----------
__global__ __launch_bounds__(256) void k_gemmA(const unsigned short* __restrict__ ebf,
    const unsigned short* __restrict__ W0T, float* __restrict__ part){
  __shared__ unsigned short Al[64*64];
  __shared__ unsigned short Bl[128*64];
  int bid = blockIdx.x;
  int mt = bid & 3, nt = (bid >> 2) & 15, kw = bid >> 6;
  int m0 = mt * 64, n0 = nt * 128, k0 = kw * 2048;
  int t = threadIdx.x, lane = t & 63, w = t >> 6;
  int wm = w >> 1, wn = w & 1;     // wave tile 32 x 64
  f32x4 acc[2][4];
  #pragma unroll
  for (int m = 0; m < 2; ++m)
    #pragma unroll
    for (int n = 0; n < 4; ++n) acc[m][n] = (f32x4){0.f,0.f,0.f,0.f};

  for (int it = 0; it < 32; ++it){
    int kb = k0 + it * 64;
    __syncthreads();
    #pragma unroll
    for (int c = 0; c < 2; ++c){     // A: 64x64, 8 chunks of 8 rows
      int q = w * 2 + c;
      int row = q * 8 + (lane >> 3);
      gl_lds16(ebf + (size_t)(m0 + row) * LE_ + kb + (lane & 7) * 8, &Al[q * 512]);
    }
    #pragma unroll
    for (int c = 0; c < 4; ++c){     // B: 128x64, 16 chunks
      int q = w * 4 + c;
      int row = q * 8 + (lane >> 3);
      gl_lds16(W0T + (size_t)(n0 + row) * DIN_ + kb + (lane & 7) * 8, &Bl[q * 512]);
    }
    __syncthreads();
    #pragma unroll
    for (int ks = 0; ks < 2; ++ks){
      short8_t af[2], bfr[4];
      #pragma unroll
      for (int m = 0; m < 2; ++m)
        af[m] = *reinterpret_cast<const short8_t*>(&Al[(wm*32 + m*16 + (lane & 15))*64 + ks*32 + (lane >> 4)*8]);
      #pragma unroll
      for (int n = 0; n < 4; ++n)
        bfr[n] = *reinterpret_cast<const short8_t*>(&Bl[(wn*64 + n*16 + (lane & 15))*64 + ks*32 + (lane >> 4)*8]);
      #pragma unroll
      for (int m = 0; m < 2; ++m)
        #pragma unroll
        for (int n = 0; n < 4; ++n) acc[m][n] = mfma16(af[m], bfr[n], acc[m][n]);
    }
  }
  float* P = part + (size_t)kw * B_ * H0_;
  #pragma unroll
  for (int m = 0; m < 2; ++m)
    #pragma unroll
    for (int n = 0; n < 4; ++n)
      #pragma unroll
      for (int i = 0; i < 4; ++i){
        int r = m0 + wm*32 + m*16 + (lane >> 4)*4 + i;
        int c = n0 + wn*64 + n*16 + (lane & 15);
        P[(size_t)r * H0_ + c] = acc[m][n][i];
      }
}

// ---------- base = b0 + sv@W_snt + sum_k part[k] ----------
__global__ __launch_bounds__(256) void k_base(const int* __restrict__ sid,
    const float* __restrict__ stab, const float* __restrict__ W0,
    const float* __restrict__ b0, const float* __restrict__ part,
    float* __restrict__ base){
  int idx = blockIdx.x * 256 + threadIdx.x;
  int b = idx >> 11, h = idx & 2047;
  const float* sv = stab + sid[b] * S_;
  float acc = b0[h];
  #pragma unroll
  for (int s = 0; s < S_; ++s) acc += sv[s] * W0[(size_t)(LE_ + s) * H0_ + h];
  #pragma unroll
  for (int kw = 0; kw < 4; ++kw) acc += part[(size_t)kw * B_ * H0_ + idx];
  base[idx] = acc;
}

// ---------- h0c = relu(base + ebf_gathered @ W_word), compacted rows ----------
__global__ __launch_bounds__(256) void k_h0(const unsigned short* __restrict__ ebf,
    const unsigned short* __restrict__ W0T, const float* __restrict__ base,
    const int* __restrict__ rowmap, const int* __restrict__ meta,
    unsigned short* __restrict__ h0c){
  int m0 = blockIdx.x * 128;
  if (m0 >= meta[1]) return;
  int n0 = blockIdx.y * 128;
  __shared__ char smem[65536];
  unsigned short* Alds = (unsigned short*)smem;            // [128][128]
  unsigned short* Blds = (unsigned short*)(smem + 32768);  // [128][128]
  int t = threadIdx.x, lane = t & 63, w = t >> 6;
  int wm = w >> 1, wn = w & 1;   // wave tile 64 x 64

  #pragma unroll
  for (int c = 0; c < 8; ++c){   // A: 128 rows x 128 k (gathered), 32 chunks of 4 rows
    int q = w * 8 + c;
    int row = q * 4 + (lane >> 4);
    int rm = rowmap[m0 + row];
    gl_lds16(ebf + (size_t)rm * E_ + (lane & 15) * 8, &Alds[q * 512]);
  }
  #pragma unroll
  for (int c = 0; c < 8; ++c){   // B: W_word^T rows n0..n0+127, k=0..127
    int q = w * 8 + c;
    int row = q * 4 + (lane >> 4);
    gl_lds16(W0T + (size_t)(n0 + row) * DIN_ + (LE_ + S_) + (lane & 15) * 8, &Blds[q * 512]);
  }
  __syncthreads();

  f32x4 acc[4][4];
  #pragma unroll
  for (int m = 0; m < 4; ++m)
    #pragma unroll
    for (int n = 0; n < 4; ++n) acc[m][n] = (f32x4){0.f,0.f,0.f,0.f};
  #pragma unroll
  for (int ks = 0; ks < 4; ++ks){
    short8_t af[4], bfr[4];
    #pragma unroll
    for (int m = 0; m < 4; ++m)
      af[m] = *reinterpret_cast<const short8_t*>(&Alds[(wm*64 + m*16 + (lane & 15))*128 + ks*32 + (lane >> 4)*8]);
    #pragma unroll
    for (int n = 0; n < 4; ++n)
      bfr[n] = *reinterpret_cast<const short8_t*>(&Blds[(wn*64 + n*16 + (lane & 15))*128 + ks*32 + (lane >> 4)*8]);
    #pragma unroll
    for (int m = 0; m < 4; ++m)
      #pragma unroll
      for (int n = 0; n < 4; ++n) acc[m][n] = mfma16(af[m], bfr[n], acc[m][n]);
  }
  __syncthreads();   // done reading A/B tiles; reuse smem as Hs[128][136]
  unsigned short* Hs = (unsigned short*)smem;
  #pragma unroll
  for (int m = 0; m < 4; ++m)
    #pragma unroll
    for (int i = 0; i < 4; ++i){
      int row_l = wm*64 + m*16 + (lane >> 4)*4 + i;
      int rm = rowmap[m0 + row_l];
      const float* bb = base + (size_t)(rm >> 6) * H0_ + n0;
      #pragma unroll
      for (int n = 0; n < 4; ++n){
        int col_l = wn*64 + n*16 + (lane & 15);
        float vv = acc[m][n][i] + bb[col_l];
        Hs[row_l * 136 + col_l] = f2bf(vv > 0.f ? vv : 0.f);
      }
    }
  __syncthreads();
  int row = t >> 1, half = t & 1;
  const unsigned short* hp = Hs + row * 136 + half * 64;
  unsigned short* gp = h0c + (size_t)(m0 + row) * H0_ + n0 + half * 64;
  #pragma unroll
  for (int j = 0; j < 8; ++j)
    *reinterpret_cast<short8_t*>(gp + j * 8) = *reinterpret_cast<const short8_t*>(hp + j * 8);
}

// ---------- h1 GEMM + relu + Wp-dot epilogue -> logitc atomics ----------
__global__ __launch_bounds__(256) void k_h1(const unsigned short* __restrict__ h0c,
    const unsigned short* __restrict__ W1T, const float* __restrict__ b1,
    const float* __restrict__ Wp, const int* __restrict__ meta,
    float* __restrict__ logitc){
  int m0 = blockIdx.x * 128;
  if (m0 >= meta[1]) return;
  int n0 = blockIdx.y * 128;
  __shared__ unsigned short Al[128*64];
  __shared__ unsigned short Bl[128*64];
  int t = threadIdx.x, lane = t & 63, w = t >> 6;
  int wm = w >> 1, wn = w & 1;   // wave tile 64 x 64
  f32x4 acc[4][4];
  #pragma unroll
  for (int m = 0; m < 4; ++m)
    #pragma unroll
    for (int n = 0; n < 4; ++n) acc[m][n] = (f32x4){0.f,0.f,0.f,0.f};

  for (int it = 0; it < 32; ++it){
    int kb = it * 64;
    __syncthreads();
    #pragma unroll
    for (int c = 0; c < 4; ++c){
      int q = w * 4 + c;
      int row = q * 8 + (lane >> 3);
      gl_lds16(h0c + (size_t)(m0 + row) * H0_ + kb + (lane & 7) * 8, &Al[q * 512]);
    }
    #pragma unroll
    for (int c = 0; c < 4; ++c){
      int q = w * 4 + c;
      int row = q * 8 + (lane >> 3);
      gl_lds16(W1T + (size_t)(n0 + row) * H0_ + kb + (lane & 7) * 8, &Bl[q * 512]);
    }
    __syncthreads();
    #pragma unroll
    for (int ks = 0; ks < 2; ++ks){
      short8_t af[4], bfr[4];
      #pragma unroll
      for (int m = 0; m < 4; ++m)
        af[m] = *reinterpret_cast<const short8_t*>(&Al[(wm*64 + m*16 + (lane & 15))*64 + ks*32 + (lane >> 4)*8]);
      #pragma unroll
      for (int n = 0; n < 4; ++n)
        bfr[n] = *reinterpret_cast<const short8_t*>(&Bl[(wn*64 + n*16 + (lane & 15))*64 + ks*32 + (lane >> 4)*8]);
      #pragma unroll
      for (int m = 0; m < 4; ++m)
        #pragma unroll
        for (int n = 0; n < 4; ++n) acc[m][n] = mfma16(af[m], bfr[n], acc[m][n]);
    }
  }
  // epilogue: relu(acc + b1) . Wp, reduce over 16 cols, atomic per row
  float b1v[4], wpv[4];
  #pragma unroll
  for (int n = 0; n < 4; ++n){
    int col = n0 + wn*64 + n*16 + (lane & 15);
    b1v[n] = b1[col]; wpv[n] = Wp[col];
  }
  #pragma unroll
  for (int m = 0; m < 4; ++m)
    #pragma unroll
    for (int i = 0; i < 4; ++i){
      float p = 0.f;
      #pragma unroll
      for (int n = 0; n < 4; ++n){
        float h = acc[m][n][i] + b1v[n];
        h = h > 0.f ? h : 0.f;
        p += h * wpv[n];
      }
      p += __shfl_xor(p, 1); p += __shfl_xor(p, 2);
      p += __shfl_xor(p, 4); p += __shfl_xor(p, 8);
      if ((lane & 15) == 0)
        atomicAdd(&logitc[m0 + wm*64 + m*16 + (lane >> 4)*4 + i], p);
    }
}

// ---------- scatter logits -> sigmoid output ----------
__global__ __launch_bounds__(256) void k_finish(const int* __restrict__ lens,
    const int* __restrict__ offs, const float* __restrict__ logitc,
    const float* __restrict__ bp, float* __restrict__ out){
  int idx = blockIdx.x * 256 + threadIdx.x;
  int b = idx >> 6, l = idx & 63;
  float x = bp[0];
  if (l < lens[b]) x += logitc[offs[b] + l];
  out[idx] = 1.f / (1.f + expf(-x));
}

extern "C" void kernel_launch(void* const* d_in, const int* in_sizes, int n_in,
                              void* d_out, int out_size, void* d_ws, size_t ws_size,
                              hipStream_t stream){
  const int*   text = (const int*)d_in[0];
  const int*   lens = (const int*)d_in[1];
  const int*   sid  = (const int*)d_in[2];
  const float* emb  = (const float*)d_in[3];
  const float* stab = (const float*)d_in[4];
  const float* W0   = (const float*)d_in[5];
  const float* b0   = (const float*)d_in[6];
  const float* W1   = (const float*)d_in[7];
  const float* b1   = (const float*)d_in[8];
  const float* Wp   = (const float*)d_in[9];
  const float* bp   = (const float*)d_in[10];
  float* out = (float*)d_out;

  char* ws = (char*)d_ws;
  unsigned short* ebf    = (unsigned short*)(ws);               //  4,194,304
  unsigned short* W0T    = (unsigned short*)(ws + 4194304);     // 34,144,256
  unsigned short* W1T    = (unsigned short*)(ws + 38338560);    //  2,097,152
  float*          base   = (float*)(ws + 40435712);             //  2,097,152
  float*          part   = (float*)(ws + 42532864);             //  8,388,608
  float*          logitc = (float*)(ws + 50921472);             //     65,536
  int*            rowmap = (int*)(ws + 50987008);               //     65,536
  int*            offs   = (int*)(ws + 51052544);               //      1,024
  int*            meta   = (int*)(ws + 51053568);               //         64
  unsigned short* h0c    = (unsigned short*)(ws + 51054592);    // 67,108,864

  hipMemsetAsync(logitc, 0, NROW * 4, stream);
  hipLaunchKernelGGL(k_scan,      dim3(1),        dim3(256), 0, stream, lens, rowmap, offs, meta);
  hipLaunchKernelGGL(k_gather,    dim3(4096),     dim3(256), 0, stream, text, emb, ebf);
  hipLaunchKernelGGL(k_transpose_cvt, dim3(131, 32), dim3(256), 0, stream, W0, W0T, DIN_, H0_);
  hipLaunchKernelGGL(k_transpose_cvt, dim3(32, 8),   dim3(256), 0, stream, W1, W1T, H0_, H1_);
  hipLaunchKernelGGL(k_gemmA,     dim3(256),      dim3(256), 0, stream, ebf, W0T, part);
  hipLaunchKernelGGL(k_base,      dim3(2048),     dim3(256), 0, stream, sid, stab, W0, b0, part, base);
  hipLaunchKernelGGL(k_h0,        dim3(128, 16),  dim3(256), 0, stream, ebf, W0T, base, rowmap, meta, h0c);
  hipLaunchKernelGGL(k_h1,        dim3(128, 4),   dim3(256), 0, stream, h0c, W1T, b1, Wp, meta, logitc);
  hipLaunchKernelGGL(k_finish,    dim3(64),       dim3(256), 0, stream, lens, offs, logitc, bp, out);
}

// Round 5
// 250.776 us; speedup vs baseline: 1.4134x; 1.1369x over previous
//
#include <hip/hip_runtime.h>
#include <hip/hip_bf16.h>

#define B_   256
#define L_   64
#define E_   128
#define S_   16
#define H0_  2048
#define H1_  512
#define LE_  8192
#define DIN_ 8336
#define NROW 16384

typedef __attribute__((ext_vector_type(8))) short short8_t;
typedef __attribute__((ext_vector_type(4))) float f32x4;

static __device__ __forceinline__ f32x4 mfma16(short8_t a, short8_t b, f32x4 c){
  return __builtin_amdgcn_mfma_f32_16x16x32_bf16(a, b, c, 0, 0, 0);
}

static __device__ __forceinline__ unsigned short f2bf(float x){
  unsigned u = __builtin_bit_cast(unsigned, x);
  unsigned r = u + 0x7FFFu + ((u >> 16) & 1u);
  return (unsigned short)(r >> 16);
}

// async global->LDS, 16B/lane; LDS dest = wave-uniform base + lane*16
static __device__ __forceinline__ void gl_lds16(const void* g, void* l){
  __builtin_amdgcn_global_load_lds((const __attribute__((address_space(1))) unsigned*)g,
                                   (__attribute__((address_space(3))) unsigned*)l, 16, 0, 0);
}

// ---------- prefix scan over lengths -> rowmap/offs/meta ----------
__global__ __launch_bounds__(256) void k_scan(const int* __restrict__ lens,
    int* __restrict__ rowmap, int* __restrict__ offs, int* __restrict__ meta){
  __shared__ int sh[256];
  int t = threadIdx.x;
  int v = lens[t];
  sh[t] = v;
  __syncthreads();
  for (int d = 1; d < 256; d <<= 1){
    int y = (t >= d) ? sh[t - d] : 0;
    __syncthreads();
    sh[t] += y;
    __syncthreads();
  }
  int off = sh[t] - v;
  int nv = sh[255];
  offs[t] = off;
  if (t == 0){
    meta[0] = nv;
    meta[1] = (nv + 63) & ~63;     // k_h1 M coverage (64-tiles)
    meta[2] = (nv + 127) & ~127;   // k_h0 M coverage (128-tiles)
  }
  for (int l = 0; l < v; ++l) rowmap[off + l] = t * 64 + l;
  for (int i = nv + t; i < NROW; i += 256) rowmap[i] = 0;
}

// ---------- transpose + fp32->bf16 : src[R][C] -> dst[C][R] ----------
__global__ __launch_bounds__(256) void k_transpose_cvt(const float* __restrict__ src,
    unsigned short* __restrict__ dst, int R, int C){
  __shared__ unsigned short tile[64][65];
  int R0 = blockIdx.x * 64, C0 = blockIdx.y * 64;
  int t = threadIdx.x;
  int row = t >> 2, c16 = (t & 3) * 16;
  int gr = R0 + row;
  if (gr < R){
    const float* p = src + (size_t)gr * C + C0 + c16;
    #pragma unroll
    for (int j = 0; j < 16; j += 4){
      float4 v = *reinterpret_cast<const float4*>(p + j);
      tile[row][c16+j+0] = f2bf(v.x);
      tile[row][c16+j+1] = f2bf(v.y);
      tile[row][c16+j+2] = f2bf(v.z);
      tile[row][c16+j+3] = f2bf(v.w);
    }
  }
  __syncthreads();
  int orow = t >> 2, r16 = (t & 3) * 16;
  unsigned short buf[16];
  #pragma unroll
  for (int j = 0; j < 16; ++j) buf[j] = tile[r16 + j][orow];
  unsigned short* q = dst + (size_t)(C0 + orow) * R + R0 + r16;
  if (R0 + r16 + 15 < R){
    *reinterpret_cast<short8_t*>(q)     = *reinterpret_cast<short8_t*>(&buf[0]);
    *reinterpret_cast<short8_t*>(q + 8) = *reinterpret_cast<short8_t*>(&buf[8]);
  } else {
    for (int j = 0; j < 16; ++j) if (R0 + r16 + j < R) q[j] = buf[j];
  }
}

// ---------- gather + row-normalize -> bf16, one wave per (b,l) row ----------
__global__ __launch_bounds__(256) void k_gather(const int* __restrict__ tokens,
    const float* __restrict__ emb, unsigned short* __restrict__ ebf){
  int wid  = blockIdx.x * 4 + (threadIdx.x >> 6);
  int lane = threadIdx.x & 63;
  int tok  = tokens[wid];
  const float* row = emb + (size_t)tok * E_;
  float2 v = *reinterpret_cast<const float2*>(row + lane * 2);
  float ss = v.x * v.x + v.y * v.y;
  #pragma unroll
  for (int m = 1; m < 64; m <<= 1) ss += __shfl_xor(ss, m, 64);
  float nrm = sqrtf(ss);
  float scale = (nrm > 1.0f) ? 1.0f / (nrm + 1e-7f) : 1.0f;
  unsigned a = f2bf(v.x * scale), b = f2bf(v.y * scale);
  *reinterpret_cast<unsigned*>(ebf + (size_t)wid * E_ + lane * 2) = a | (b << 16);
}

// stage one 64xK-tile (A, 8-row chunks x2) + 128xK-tile (B, x4) with
// pre-swizzled source cols (inverse of read swizzle; XOR involution)
static __device__ __forceinline__ void stage64(
    const unsigned short* __restrict__ Asrc, size_t strideA, int m0,
    const unsigned short* __restrict__ Bsrc, size_t strideB, int n0,
    int kbA, int kbB, int w, int lane,
    unsigned short* Al, unsigned short* Bl){
  int rsub = lane >> 3;                    // row within 8-row chunk
  int csw  = 8 * ((lane & 7) ^ rsub);      // pre-swizzled src element col
  #pragma unroll
  for (int c = 0; c < 2; ++c){
    int q = w * 2 + c;
    gl_lds16(Asrc + (size_t)(m0 + q*8 + rsub) * strideA + kbA + csw, Al + q * 512);
  }
  #pragma unroll
  for (int c = 0; c < 4; ++c){
    int q = w * 4 + c;
    gl_lds16(Bsrc + (size_t)(n0 + q*8 + rsub) * strideB + kbB + csw, Bl + q * 512);
  }
}

// ---------- part[kw] = sent_flat @ W_sent (K-split, swizzled, 2-phase) ----------
__global__ __launch_bounds__(256, 2) void k_gemmA(const unsigned short* __restrict__ ebf,
    const unsigned short* __restrict__ W0T, float* __restrict__ part){
  __shared__ unsigned short Al[2][64*64];
  __shared__ unsigned short Bl[2][128*64];
  int bid = blockIdx.x;
  int mt = bid & 3, nt = (bid >> 2) & 15, kw = bid >> 6;
  int m0 = mt * 64, n0 = nt * 128, k0 = kw * 2048;
  int t = threadIdx.x, lane = t & 63, w = t >> 6;
  int wm = w >> 1, wn = w & 1;             // wave tile 32 x 64
  int sw = (lane & 7) * 8, hi = (lane >> 4) * 8, fr = lane & 15;
  f32x4 acc[2][4];
  #pragma unroll
  for (int m = 0; m < 2; ++m)
    #pragma unroll
    for (int n = 0; n < 4; ++n) acc[m][n] = (f32x4){0.f,0.f,0.f,0.f};

  stage64(ebf, LE_, m0, W0T, DIN_, n0, k0, k0, w, lane, Al[0], Bl[0]);
  __syncthreads();
  for (int it = 0; it < 32; ++it){
    int cur = it & 1;
    if (it + 1 < 32)
      stage64(ebf, LE_, m0, W0T, DIN_, n0, k0 + (it+1)*64, k0 + (it+1)*64,
              w, lane, Al[cur^1], Bl[cur^1]);
    #pragma unroll
    for (int ks = 0; ks < 2; ++ks){
      int col = (ks*32 + hi) ^ sw;
      short8_t af[2], bfr[4];
      #pragma unroll
      for (int m = 0; m < 2; ++m)
        af[m] = *reinterpret_cast<const short8_t*>(&Al[cur][(wm*32 + m*16 + fr)*64 + col]);
      #pragma unroll
      for (int n = 0; n < 4; ++n)
        bfr[n] = *reinterpret_cast<const short8_t*>(&Bl[cur][(wn*64 + n*16 + fr)*64 + col]);
      #pragma unroll
      for (int m = 0; m < 2; ++m)
        #pragma unroll
        for (int n = 0; n < 4; ++n) acc[m][n] = mfma16(af[m], bfr[n], acc[m][n]);
    }
    __syncthreads();
  }
  float* P = part + (size_t)kw * B_ * H0_;
  #pragma unroll
  for (int m = 0; m < 2; ++m)
    #pragma unroll
    for (int n = 0; n < 4; ++n)
      #pragma unroll
      for (int i = 0; i < 4; ++i){
        int r = m0 + wm*32 + m*16 + (lane >> 4)*4 + i;
        int c = n0 + wn*64 + n*16 + fr;
        P[(size_t)r * H0_ + c] = acc[m][n][i];
      }
}

// ---------- base = b0 + sv@W_snt + sum_k part[k] ----------
__global__ __launch_bounds__(256) void k_base(const int* __restrict__ sid,
    const float* __restrict__ stab, const float* __restrict__ W0,
    const float* __restrict__ b0, const float* __restrict__ part,
    float* __restrict__ base){
  int idx = blockIdx.x * 256 + threadIdx.x;
  int b = idx >> 11, h = idx & 2047;
  const float* sv = stab + sid[b] * S_;
  float acc = b0[h];
  #pragma unroll
  for (int s = 0; s < S_; ++s) acc += sv[s] * W0[(size_t)(LE_ + s) * H0_ + h];
  #pragma unroll
  for (int kw = 0; kw < 4; ++kw) acc += part[(size_t)kw * B_ * H0_ + idx];
  base[idx] = acc;
}

// ---------- h0c = relu(base + ebf_gathered @ W_word), compacted rows ----------
__global__ __launch_bounds__(256, 2) void k_h0(const unsigned short* __restrict__ ebf,
    const unsigned short* __restrict__ W0T, const float* __restrict__ base,
    const int* __restrict__ rowmap, const int* __restrict__ meta,
    unsigned short* __restrict__ h0c){
  int m0 = blockIdx.x * 128;
  if (m0 >= meta[2]) return;
  int n0 = blockIdx.y * 128;
  __shared__ char smem[65536];
  unsigned short* Alds = (unsigned short*)smem;            // [128][128] swizzled
  unsigned short* Blds = (unsigned short*)(smem + 32768);  // [128][128] swizzled
  int t = threadIdx.x, lane = t & 63, w = t >> 6;
  int wm = w >> 1, wn = w & 1;   // wave tile 64 x 64
  int sw = (lane & 7) * 8, hi = (lane >> 4) * 8, fr = lane & 15;

  {
    int rsub = lane >> 4;               // row within 4-row chunk
    int bc = lane & 15;
    #pragma unroll
    for (int c = 0; c < 8; ++c){        // A: 32 chunks of 4 rows (gathered)
      int q = w * 8 + c;
      int row7 = (q & 1) * 4 + rsub;
      int csw = 8 * (bc ^ row7);
      int rm = rowmap[m0 + q*4 + rsub];
      gl_lds16(ebf + (size_t)rm * E_ + csw, Alds + q * 512);
    }
    #pragma unroll
    for (int c = 0; c < 8; ++c){        // B: W_word^T rows n0..+127
      int q = w * 8 + c;
      int row7 = (q & 1) * 4 + rsub;
      int csw = 8 * (bc ^ row7);
      gl_lds16(W0T + (size_t)(n0 + q*4 + rsub) * DIN_ + (LE_ + S_) + csw, Blds + q * 512);
    }
  }
  __syncthreads();

  f32x4 acc[4][4];
  #pragma unroll
  for (int m = 0; m < 4; ++m)
    #pragma unroll
    for (int n = 0; n < 4; ++n) acc[m][n] = (f32x4){0.f,0.f,0.f,0.f};
  #pragma unroll
  for (int ks = 0; ks < 4; ++ks){
    int col = (ks*32 + hi) ^ sw;
    short8_t af[4], bfr[4];
    #pragma unroll
    for (int m = 0; m < 4; ++m)
      af[m] = *reinterpret_cast<const short8_t*>(&Alds[(wm*64 + m*16 + fr)*128 + col]);
    #pragma unroll
    for (int n = 0; n < 4; ++n)
      bfr[n] = *reinterpret_cast<const short8_t*>(&Blds[(wn*64 + n*16 + fr)*128 + col]);
    #pragma unroll
    for (int m = 0; m < 4; ++m)
      #pragma unroll
      for (int n = 0; n < 4; ++n) acc[m][n] = mfma16(af[m], bfr[n], acc[m][n]);
  }
  __syncthreads();   // tiles consumed; reuse smem as Hs[128][136]
  unsigned short* Hs = (unsigned short*)smem;
  #pragma unroll
  for (int m = 0; m < 4; ++m)
    #pragma unroll
    for (int i = 0; i < 4; ++i){
      int row_l = wm*64 + m*16 + (lane >> 4)*4 + i;
      int rm = rowmap[m0 + row_l];
      const float* bb = base + (size_t)(rm >> 6) * H0_ + n0;
      #pragma unroll
      for (int n = 0; n < 4; ++n){
        int col_l = wn*64 + n*16 + fr;
        float vv = acc[m][n][i] + bb[col_l];
        Hs[row_l * 136 + col_l] = f2bf(vv > 0.f ? vv : 0.f);
      }
    }
  __syncthreads();
  int row = t >> 1, half = t & 1;
  const unsigned short* hp = Hs + row * 136 + half * 64;
  unsigned short* gp = h0c + (size_t)(m0 + row) * H0_ + n0 + half * 64;
  #pragma unroll
  for (int j = 0; j < 8; ++j)
    *reinterpret_cast<short8_t*>(gp + j * 8) = *reinterpret_cast<const short8_t*>(hp + j * 8);
}

// ---------- h1 GEMM (64x128 tile, swizzled, 2-phase) + relu + Wp-dot ----------
__global__ __launch_bounds__(256, 2) void k_h1(const unsigned short* __restrict__ h0c,
    const unsigned short* __restrict__ W1T, const float* __restrict__ b1,
    const float* __restrict__ Wp, const int* __restrict__ meta,
    float* __restrict__ logitc){
  int m0 = blockIdx.x * 64;
  if (m0 >= meta[1]) return;
  int n0 = blockIdx.y * 128;
  __shared__ unsigned short Al[2][64*64];
  __shared__ unsigned short Bl[2][128*64];
  int t = threadIdx.x, lane = t & 63, w = t >> 6;
  int wm = w >> 1, wn = w & 1;   // wave tile 32 x 64
  int sw = (lane & 7) * 8, hi = (lane >> 4) * 8, fr = lane & 15;
  f32x4 acc[2][4];
  #pragma unroll
  for (int m = 0; m < 2; ++m)
    #pragma unroll
    for (int n = 0; n < 4; ++n) acc[m][n] = (f32x4){0.f,0.f,0.f,0.f};

  stage64(h0c, H0_, m0, W1T, H0_, n0, 0, 0, w, lane, Al[0], Bl[0]);
  __syncthreads();
  for (int it = 0; it < 32; ++it){
    int cur = it & 1;
    if (it + 1 < 32)
      stage64(h0c, H0_, m0, W1T, H0_, n0, (it+1)*64, (it+1)*64, w, lane, Al[cur^1], Bl[cur^1]);
    #pragma unroll
    for (int ks = 0; ks < 2; ++ks){
      int col = (ks*32 + hi) ^ sw;
      short8_t af[2], bfr[4];
      #pragma unroll
      for (int m = 0; m < 2; ++m)
        af[m] = *reinterpret_cast<const short8_t*>(&Al[cur][(wm*32 + m*16 + fr)*64 + col]);
      #pragma unroll
      for (int n = 0; n < 4; ++n)
        bfr[n] = *reinterpret_cast<const short8_t*>(&Bl[cur][(wn*64 + n*16 + fr)*64 + col]);
      #pragma unroll
      for (int m = 0; m < 2; ++m)
        #pragma unroll
        for (int n = 0; n < 4; ++n) acc[m][n] = mfma16(af[m], bfr[n], acc[m][n]);
    }
    __syncthreads();
  }
  // epilogue: relu(acc + b1) . Wp, reduce 16 cols, atomic per row
  float b1v[4], wpv[4];
  #pragma unroll
  for (int n = 0; n < 4; ++n){
    int col = n0 + wn*64 + n*16 + fr;
    b1v[n] = b1[col]; wpv[n] = Wp[col];
  }
  #pragma unroll
  for (int m = 0; m < 2; ++m)
    #pragma unroll
    for (int i = 0; i < 4; ++i){
      float p = 0.f;
      #pragma unroll
      for (int n = 0; n < 4; ++n){
        float h = acc[m][n][i] + b1v[n];
        h = h > 0.f ? h : 0.f;
        p += h * wpv[n];
      }
      p += __shfl_xor(p, 1); p += __shfl_xor(p, 2);
      p += __shfl_xor(p, 4); p += __shfl_xor(p, 8);
      if ((lane & 15) == 0)
        atomicAdd(&logitc[m0 + wm*32 + m*16 + (lane >> 4)*4 + i], p);
    }
}

// ---------- scatter logits -> sigmoid output ----------
__global__ __launch_bounds__(256) void k_finish(const int* __restrict__ lens,
    const int* __restrict__ offs, const float* __restrict__ logitc,
    const float* __restrict__ bp, float* __restrict__ out){
  int idx = blockIdx.x * 256 + threadIdx.x;
  int b = idx >> 6, l = idx & 63;
  float x = bp[0];
  if (l < lens[b]) x += logitc[offs[b] + l];
  out[idx] = 1.f / (1.f + expf(-x));
}

extern "C" void kernel_launch(void* const* d_in, const int* in_sizes, int n_in,
                              void* d_out, int out_size, void* d_ws, size_t ws_size,
                              hipStream_t stream){
  const int*   text = (const int*)d_in[0];
  const int*   lens = (const int*)d_in[1];
  const int*   sid  = (const int*)d_in[2];
  const float* emb  = (const float*)d_in[3];
  const float* stab = (const float*)d_in[4];
  const float* W0   = (const float*)d_in[5];
  const float* b0   = (const float*)d_in[6];
  const float* W1   = (const float*)d_in[7];
  const float* b1   = (const float*)d_in[8];
  const float* Wp   = (const float*)d_in[9];
  const float* bp   = (const float*)d_in[10];
  float* out = (float*)d_out;

  char* ws = (char*)d_ws;
  unsigned short* ebf    = (unsigned short*)(ws);               //  4,194,304
  unsigned short* W0T    = (unsigned short*)(ws + 4194304);     // 34,144,256
  unsigned short* W1T    = (unsigned short*)(ws + 38338560);    //  2,097,152
  float*          base   = (float*)(ws + 40435712);             //  2,097,152
  float*          part   = (float*)(ws + 42532864);             //  8,388,608
  float*          logitc = (float*)(ws + 50921472);             //     65,536
  int*            rowmap = (int*)(ws + 50987008);               //     65,536
  int*            offs   = (int*)(ws + 51052544);               //      1,024
  int*            meta   = (int*)(ws + 51053568);               //         64
  unsigned short* h0c    = (unsigned short*)(ws + 51054592);    // 67,108,864

  hipMemsetAsync(logitc, 0, NROW * 4, stream);
  hipLaunchKernelGGL(k_scan,      dim3(1),        dim3(256), 0, stream, lens, rowmap, offs, meta);
  hipLaunchKernelGGL(k_gather,    dim3(4096),     dim3(256), 0, stream, text, emb, ebf);
  hipLaunchKernelGGL(k_transpose_cvt, dim3(131, 32), dim3(256), 0, stream, W0, W0T, DIN_, H0_);
  hipLaunchKernelGGL(k_transpose_cvt, dim3(32, 8),   dim3(256), 0, stream, W1, W1T, H0_, H1_);
  hipLaunchKernelGGL(k_gemmA,     dim3(256),      dim3(256), 0, stream, ebf, W0T, part);
  hipLaunchKernelGGL(k_base,      dim3(2048),     dim3(256), 0, stream, sid, stab, W0, b0, part, base);
  hipLaunchKernelGGL(k_h0,        dim3(128, 16),  dim3(256), 0, stream, ebf, W0T, base, rowmap, meta, h0c);
  hipLaunchKernelGGL(k_h1,        dim3(256, 4),   dim3(256), 0, stream, h0c, W1T, b1, Wp, meta, logitc);
  hipLaunchKernelGGL(k_finish,    dim3(64),       dim3(256), 0, stream, lens, offs, logitc, bp, out);
}

// Round 8
// 243.361 us; speedup vs baseline: 1.4565x; 1.0305x over previous
//
#include <hip/hip_runtime.h>
#include <hip/hip_bf16.h>

#define B_   256
#define L_   64
#define E_   128
#define S_   16
#define H0_  2048
#define H1_  512
#define LE_  8192
#define DIN_ 8336
#define NROW 16384

typedef __attribute__((ext_vector_type(8))) short short8_t;
typedef __attribute__((ext_vector_type(4))) float f32x4;

static __device__ __forceinline__ f32x4 mfma16(short8_t a, short8_t b, f32x4 c){
  return __builtin_amdgcn_mfma_f32_16x16x32_bf16(a, b, c, 0, 0, 0);
}

static __device__ __forceinline__ unsigned short f2bf(float x){
  unsigned u = __builtin_bit_cast(unsigned, x);
  unsigned r = u + 0x7FFFu + ((u >> 16) & 1u);
  return (unsigned short)(r >> 16);
}

// async global->LDS, 16B/lane; LDS dest = wave-uniform base + lane*16
static __device__ __forceinline__ void gl_lds16(const void* g, void* l){
  __builtin_amdgcn_global_load_lds((const __attribute__((address_space(1))) unsigned*)g,
                                   (__attribute__((address_space(3))) unsigned*)l, 16, 0, 0);
}

// ---------- prefix scan over lengths -> offs/meta ----------
__global__ __launch_bounds__(256) void k_scan(const int* __restrict__ lens,
    int* __restrict__ offs, int* __restrict__ meta){
  __shared__ int sh[256];
  int t = threadIdx.x;
  int v = lens[t];
  sh[t] = v;
  __syncthreads();
  for (int d = 1; d < 256; d <<= 1){
    int y = (t >= d) ? sh[t - d] : 0;
    __syncthreads();
    sh[t] += y;
    __syncthreads();
  }
  int off = sh[t] - v;
  int nv = sh[255];
  offs[t] = off;
  if (t == 0){
    meta[0] = nv;
    meta[1] = (nv + 63) & ~63;     // k_h1 M coverage (64-tiles)
    meta[2] = (nv + 127) & ~127;   // k_h0 M coverage (128-tiles)
  }
}

// ---------- parallel rowmap fill + logitc zero ----------
__global__ __launch_bounds__(256) void k_rowfill(const int* __restrict__ lens,
    const int* __restrict__ offs, const int* __restrict__ meta,
    int* __restrict__ rowmap, float* __restrict__ logitc){
  int idx = blockIdx.x * 256 + threadIdx.x;   // 0..16383
  int b = idx >> 6, l = idx & 63;
  logitc[idx] = 0.f;
  if (l < lens[b]) rowmap[offs[b] + l] = idx;  // targets [0, nv)
  if (idx >= meta[0]) rowmap[idx] = 0;         // targets [nv, 16384) - disjoint
}

// ---------- transpose + fp32->bf16 : src[R][C] -> dst[C][R] ----------
__global__ __launch_bounds__(256) void k_transpose_cvt(const float* __restrict__ src,
    unsigned short* __restrict__ dst, int R, int C){
  __shared__ unsigned short tile[64][65];
  int R0 = blockIdx.x * 64, C0 = blockIdx.y * 64;
  int t = threadIdx.x;
  int row = t >> 2, c16 = (t & 3) * 16;
  int gr = R0 + row;
  if (gr < R){
    const float* p = src + (size_t)gr * C + C0 + c16;
    #pragma unroll
    for (int j = 0; j < 16; j += 4){
      float4 v = *reinterpret_cast<const float4*>(p + j);
      tile[row][c16+j+0] = f2bf(v.x);
      tile[row][c16+j+1] = f2bf(v.y);
      tile[row][c16+j+2] = f2bf(v.z);
      tile[row][c16+j+3] = f2bf(v.w);
    }
  }
  __syncthreads();
  int orow = t >> 2, r16 = (t & 3) * 16;
  unsigned short buf[16];
  #pragma unroll
  for (int j = 0; j < 16; ++j) buf[j] = tile[r16 + j][orow];
  unsigned short* q = dst + (size_t)(C0 + orow) * R + R0 + r16;
  if (R0 + r16 + 15 < R){
    *reinterpret_cast<short8_t*>(q)     = *reinterpret_cast<short8_t*>(&buf[0]);
    *reinterpret_cast<short8_t*>(q + 8) = *reinterpret_cast<short8_t*>(&buf[8]);
  } else {
    for (int j = 0; j < 16; ++j) if (R0 + r16 + j < R) q[j] = buf[j];
  }
}

// ---------- gather + row-normalize -> bf16, one wave per (b,l) row ----------
__global__ __launch_bounds__(256) void k_gather(const int* __restrict__ tokens,
    const float* __restrict__ emb, unsigned short* __restrict__ ebf){
  int wid  = blockIdx.x * 4 + (threadIdx.x >> 6);
  int lane = threadIdx.x & 63;
  int tok  = tokens[wid];
  const float* row = emb + (size_t)tok * E_;
  float2 v = *reinterpret_cast<const float2*>(row + lane * 2);
  float ss = v.x * v.x + v.y * v.y;
  #pragma unroll
  for (int m = 1; m < 64; m <<= 1) ss += __shfl_xor(ss, m, 64);
  float nrm = sqrtf(ss);
  float scale = (nrm > 1.0f) ? 1.0f / (nrm + 1e-7f) : 1.0f;
  unsigned a = f2bf(v.x * scale), b = f2bf(v.y * scale);
  *reinterpret_cast<unsigned*>(ebf + (size_t)wid * E_ + lane * 2) = a | (b << 16);
}

// stage one 64xK-tile (A) + 128xK-tile (B), pre-swizzled source cols
static __device__ __forceinline__ void stage64(
    const unsigned short* __restrict__ Asrc, size_t strideA, int m0,
    const unsigned short* __restrict__ Bsrc, size_t strideB, int n0,
    int kbA, int kbB, int w, int lane,
    unsigned short* Al, unsigned short* Bl){
  int rsub = lane >> 3;                    // row within 8-row chunk
  int csw  = 8 * ((lane & 7) ^ rsub);      // pre-swizzled src element col
  #pragma unroll
  for (int c = 0; c < 2; ++c){
    int q = w * 2 + c;
    gl_lds16(Asrc + (size_t)(m0 + q*8 + rsub) * strideA + kbA + csw, Al + q * 512);
  }
  #pragma unroll
  for (int c = 0; c < 4; ++c){
    int q = w * 4 + c;
    gl_lds16(Bsrc + (size_t)(n0 + q*8 + rsub) * strideB + kbB + csw, Bl + q * 512);
  }
}

// ---------- part[kw] = sent_flat @ W_sent (K-split, swizzled, 2-phase) ----------
__global__ __launch_bounds__(256, 3) void k_gemmA(const unsigned short* __restrict__ ebf,
    const unsigned short* __restrict__ W0T, float* __restrict__ part){
  __shared__ unsigned short Al[2][64*64];
  __shared__ unsigned short Bl[2][128*64];
  int bid = blockIdx.x;
  int mt = bid & 3, nt = (bid >> 2) & 15, kw = bid >> 6;
  int m0 = mt * 64, n0 = nt * 128, k0 = kw * 2048;
  int t = threadIdx.x, lane = t & 63, w = t >> 6;
  int wm = w >> 1, wn = w & 1;             // wave tile 32 x 64
  int sw = (lane & 7) * 8, hi = (lane >> 4) * 8, fr = lane & 15;
  f32x4 acc[2][4];
  #pragma unroll
  for (int m = 0; m < 2; ++m)
    #pragma unroll
    for (int n = 0; n < 4; ++n) acc[m][n] = (f32x4){0.f,0.f,0.f,0.f};

  stage64(ebf, LE_, m0, W0T, DIN_, n0, k0, k0, w, lane, Al[0], Bl[0]);
  __syncthreads();
  for (int it = 0; it < 32; ++it){
    int cur = it & 1;
    if (it + 1 < 32)
      stage64(ebf, LE_, m0, W0T, DIN_, n0, k0 + (it+1)*64, k0 + (it+1)*64,
              w, lane, Al[cur^1], Bl[cur^1]);
    #pragma unroll
    for (int ks = 0; ks < 2; ++ks){
      int col = (ks*32 + hi) ^ sw;
      short8_t af[2], bfr[4];
      #pragma unroll
      for (int m = 0; m < 2; ++m)
        af[m] = *reinterpret_cast<const short8_t*>(&Al[cur][(wm*32 + m*16 + fr)*64 + col]);
      #pragma unroll
      for (int n = 0; n < 4; ++n)
        bfr[n] = *reinterpret_cast<const short8_t*>(&Bl[cur][(wn*64 + n*16 + fr)*64 + col]);
      #pragma unroll
      for (int m = 0; m < 2; ++m)
        #pragma unroll
        for (int n = 0; n < 4; ++n) acc[m][n] = mfma16(af[m], bfr[n], acc[m][n]);
    }
    __syncthreads();
  }
  float* P = part + (size_t)kw * B_ * H0_;
  #pragma unroll
  for (int m = 0; m < 2; ++m)
    #pragma unroll
    for (int n = 0; n < 4; ++n)
      #pragma unroll
      for (int i = 0; i < 4; ++i){
        int r = m0 + wm*32 + m*16 + (lane >> 4)*4 + i;
        int c = n0 + wn*64 + n*16 + fr;
        P[(size_t)r * H0_ + c] = acc[m][n][i];
      }
}

// ---------- base = b0 + sv@W_snt + sum_k part[k] ----------
__global__ __launch_bounds__(256) void k_base(const int* __restrict__ sid,
    const float* __restrict__ stab, const float* __restrict__ W0,
    const float* __restrict__ b0, const float* __restrict__ part,
    float* __restrict__ base){
  int idx = blockIdx.x * 256 + threadIdx.x;
  int b = idx >> 11, h = idx & 2047;
  const float* sv = stab + sid[b] * S_;
  float acc = b0[h];
  #pragma unroll
  for (int s = 0; s < S_; ++s) acc += sv[s] * W0[(size_t)(LE_ + s) * H0_ + h];
  #pragma unroll
  for (int kw = 0; kw < 4; ++kw) acc += part[(size_t)kw * B_ * H0_ + idx];
  base[idx] = acc;
}

// ---------- h0c = relu(base + ebf_gathered @ W_word), compacted rows ----------
// 32KB LDS single-buffer, two K=64 halves, direct global stores (no Hs).
__global__ __launch_bounds__(256, 4) void k_h0(const unsigned short* __restrict__ ebf,
    const unsigned short* __restrict__ W0T, const float* __restrict__ base,
    const int* __restrict__ rowmap, const int* __restrict__ meta,
    unsigned short* __restrict__ h0c){
  int bid = blockIdx.x;
  int n0 = (bid & 15) * 128;     // y-fastest: siblings sharing A-tile adjacent
  int m0 = (bid >> 4) * 128;
  if (m0 >= meta[2]) return;
  __shared__ unsigned short Alds[128*64];
  __shared__ unsigned short Blds[128*64];
  int t = threadIdx.x, lane = t & 63, w = t >> 6;
  int wm = w >> 1, wn = w & 1;   // wave tile 64 x 64
  int sw = (lane & 7) * 8, hi = (lane >> 4) * 8, fr = lane & 15;
  int rsub = lane >> 3;
  int csw = 8 * ((lane & 7) ^ rsub);

  int rmv[4];
  #pragma unroll
  for (int c = 0; c < 4; ++c) rmv[c] = rowmap[m0 + (w*4 + c)*8 + rsub];

  f32x4 acc[4][4];
  #pragma unroll
  for (int m = 0; m < 4; ++m)
    #pragma unroll
    for (int n = 0; n < 4; ++n) acc[m][n] = (f32x4){0.f,0.f,0.f,0.f};

  for (int kh = 0; kh < 2; ++kh){
    if (kh) __syncthreads();     // all reads of previous half done
    int kb = kh * 64;
    #pragma unroll
    for (int c = 0; c < 4; ++c){      // A: 16 chunks of 8 rows (gathered)
      int q = w * 4 + c;
      gl_lds16(ebf + (size_t)rmv[c] * E_ + kb + csw, Alds + q * 512);
    }
    #pragma unroll
    for (int c = 0; c < 4; ++c){      // B: W_word^T rows n0..+127
      int q = w * 4 + c;
      gl_lds16(W0T + (size_t)(n0 + q*8 + rsub) * DIN_ + (LE_ + S_) + kb + csw,
               Blds + q * 512);
    }
    __syncthreads();
    #pragma unroll
    for (int ks = 0; ks < 2; ++ks){
      int col = (ks*32 + hi) ^ sw;
      short8_t af[4], bfr[4];
      #pragma unroll
      for (int m = 0; m < 4; ++m)
        af[m] = *reinterpret_cast<const short8_t*>(&Alds[(wm*64 + m*16 + fr)*64 + col]);
      #pragma unroll
      for (int n = 0; n < 4; ++n)
        bfr[n] = *reinterpret_cast<const short8_t*>(&Blds[(wn*64 + n*16 + fr)*64 + col]);
      #pragma unroll
      for (int m = 0; m < 4; ++m)
        #pragma unroll
        for (int n = 0; n < 4; ++n) acc[m][n] = mfma16(af[m], bfr[n], acc[m][n]);
    }
  }
  // epilogue: add base, relu, direct bf16 stores
  #pragma unroll
  for (int m = 0; m < 4; ++m)
    #pragma unroll
    for (int i = 0; i < 4; ++i){
      int row_l = wm*64 + m*16 + (lane >> 4)*4 + i;
      int rm = rowmap[m0 + row_l];
      const float* bb = base + (size_t)(rm >> 6) * H0_ + n0;
      unsigned short* gp = h0c + (size_t)(m0 + row_l) * H0_ + n0;
      #pragma unroll
      for (int n = 0; n < 4; ++n){
        int col_l = wn*64 + n*16 + fr;
        float vv = acc[m][n][i] + bb[col_l];
        gp[col_l] = f2bf(vv > 0.f ? vv : 0.f);
      }
    }
}

// ---------- h1 GEMM (64x128 tile, swizzled, 2-phase) + relu + Wp-dot ----------
__global__ __launch_bounds__(256, 3) void k_h1(const unsigned short* __restrict__ h0c,
    const unsigned short* __restrict__ W1T, const float* __restrict__ b1,
    const float* __restrict__ Wp, const int* __restrict__ meta,
    float* __restrict__ logitc){
  int bid = blockIdx.x;
  int n0 = (bid & 3) * 128;      // y-fastest: siblings sharing A-tile adjacent
  int m0 = (bid >> 2) * 64;
  if (m0 >= meta[1]) return;
  __shared__ unsigned short Al[2][64*64];
  __shared__ unsigned short Bl[2][128*64];
  int t = threadIdx.x, lane = t & 63, w = t >> 6;
  int wm = w >> 1, wn = w & 1;   // wave tile 32 x 64
  int sw = (lane & 7) * 8, hi = (lane >> 4) * 8, fr = lane & 15;
  f32x4 acc[2][4];
  #pragma unroll
  for (int m = 0; m < 2; ++m)
    #pragma unroll
    for (int n = 0; n < 4; ++n) acc[m][n] = (f32x4){0.f,0.f,0.f,0.f};

  stage64(h0c, H0_, m0, W1T, H0_, n0, 0, 0, w, lane, Al[0], Bl[0]);
  __syncthreads();
  for (int it = 0; it < 32; ++it){
    int cur = it & 1;
    if (it + 1 < 32)
      stage64(h0c, H0_, m0, W1T, H0_, n0, (it+1)*64, (it+1)*64, w, lane, Al[cur^1], Bl[cur^1]);
    #pragma unroll
    for (int ks = 0; ks < 2; ++ks){
      int col = (ks*32 + hi) ^ sw;
      short8_t af[2], bfr[4];
      #pragma unroll
      for (int m = 0; m < 2; ++m)
        af[m] = *reinterpret_cast<const short8_t*>(&Al[cur][(wm*32 + m*16 + fr)*64 + col]);
      #pragma unroll
      for (int n = 0; n < 4; ++n)
        bfr[n] = *reinterpret_cast<const short8_t*>(&Bl[cur][(wn*64 + n*16 + fr)*64 + col]);
      #pragma unroll
      for (int m = 0; m < 2; ++m)
        #pragma unroll
        for (int n = 0; n < 4; ++n) acc[m][n] = mfma16(af[m], bfr[n], acc[m][n]);
    }
    __syncthreads();
  }
  // epilogue: relu(acc + b1) . Wp, reduce 16 cols, atomic per row
  float b1v[4], wpv[4];
  #pragma unroll
  for (int n = 0; n < 4; ++n){
    int col = n0 + wn*64 + n*16 + fr;
    b1v[n] = b1[col]; wpv[n] = Wp[col];
  }
  #pragma unroll
  for (int m = 0; m < 2; ++m)
    #pragma unroll
    for (int i = 0; i < 4; ++i){
      float p = 0.f;
      #pragma unroll
      for (int n = 0; n < 4; ++n){
        float h = acc[m][n][i] + b1v[n];
        h = h > 0.f ? h : 0.f;
        p += h * wpv[n];
      }
      p += __shfl_xor(p, 1); p += __shfl_xor(p, 2);
      p += __shfl_xor(p, 4); p += __shfl_xor(p, 8);
      if ((lane & 15) == 0)
        atomicAdd(&logitc[m0 + wm*32 + m*16 + (lane >> 4)*4 + i], p);
    }
}

// ---------- scatter logits -> sigmoid output ----------
__global__ __launch_bounds__(256) void k_finish(const int* __restrict__ lens,
    const int* __restrict__ offs, const float* __restrict__ logitc,
    const float* __restrict__ bp, float* __restrict__ out){
  int idx = blockIdx.x * 256 + threadIdx.x;
  int b = idx >> 6, l = idx & 63;
  float x = bp[0];
  if (l < lens[b]) x += logitc[offs[b] + l];
  out[idx] = 1.f / (1.f + expf(-x));
}

extern "C" void kernel_launch(void* const* d_in, const int* in_sizes, int n_in,
                              void* d_out, int out_size, void* d_ws, size_t ws_size,
                              hipStream_t stream){
  const int*   text = (const int*)d_in[0];
  const int*   lens = (const int*)d_in[1];
  const int*   sid  = (const int*)d_in[2];
  const float* emb  = (const float*)d_in[3];
  const float* stab = (const float*)d_in[4];
  const float* W0   = (const float*)d_in[5];
  const float* b0   = (const float*)d_in[6];
  const float* W1   = (const float*)d_in[7];
  const float* b1   = (const float*)d_in[8];
  const float* Wp   = (const float*)d_in[9];
  const float* bp   = (const float*)d_in[10];
  float* out = (float*)d_out;

  char* ws = (char*)d_ws;
  unsigned short* ebf    = (unsigned short*)(ws);               //  4,194,304
  unsigned short* W0T    = (unsigned short*)(ws + 4194304);     // 34,144,256
  unsigned short* W1T    = (unsigned short*)(ws + 38338560);    //  2,097,152
  float*          base   = (float*)(ws + 40435712);             //  2,097,152
  float*          part   = (float*)(ws + 42532864);             //  8,388,608
  float*          logitc = (float*)(ws + 50921472);             //     65,536
  int*            rowmap = (int*)(ws + 50987008);               //     65,536
  int*            offs   = (int*)(ws + 51052544);               //      1,024
  int*            meta   = (int*)(ws + 51053568);               //         64
  unsigned short* h0c    = (unsigned short*)(ws + 51054592);    // 67,108,864

  hipLaunchKernelGGL(k_scan,      dim3(1),        dim3(256), 0, stream, lens, offs, meta);
  hipLaunchKernelGGL(k_rowfill,   dim3(64),       dim3(256), 0, stream, lens, offs, meta, rowmap, logitc);
  hipLaunchKernelGGL(k_gather,    dim3(4096),     dim3(256), 0, stream, text, emb, ebf);
  hipLaunchKernelGGL(k_transpose_cvt, dim3(131, 32), dim3(256), 0, stream, W0, W0T, DIN_, H0_);
  hipLaunchKernelGGL(k_transpose_cvt, dim3(32, 8),   dim3(256), 0, stream, W1, W1T, H0_, H1_);
  hipLaunchKernelGGL(k_gemmA,     dim3(256),      dim3(256), 0, stream, ebf, W0T, part);
  hipLaunchKernelGGL(k_base,      dim3(2048),     dim3(256), 0, stream, sid, stab, W0, b0, part, base);
  hipLaunchKernelGGL(k_h0,        dim3(2048),     dim3(256), 0, stream, ebf, W0T, base, rowmap, meta, h0c);
  hipLaunchKernelGGL(k_h1,        dim3(1024),     dim3(256), 0, stream, h0c, W1T, b1, Wp, meta, logitc);
  hipLaunchKernelGGL(k_finish,    dim3(64),       dim3(256), 0, stream, lens, offs, logitc, bp, out);
}